// Round 5
// baseline (142.571 us; speedup 1.0000x reference)
//
#include <hip/hip_runtime.h>

// XCorrExt: B=32, S=160000, N=320, H=160, TAU=257, LAG_CUT=33
// out[b,f,tau-33] = 2*num/(e0 + e_tau + 1e-5), tau in [33,256]
// num[f,tau] = sum_n ext_f[tau+n]*frame_f[n]; frame_f[n] = z[160f+n]
// ext_f[t] = z[160f+t] (t<320) | z[160f+t-160] (t in [320,612)) | f=999: wrap x[t-320]
//
// R5: (1) live set fits 64 VGPRs (allocator always targets 64; R2-R4 spilled):
// 16 lanes/frame x 16 taus, acc[16]+W[20]+FQ[2][4]+misc ~= 58. (2) LDS "D"
// layout: each 160-half stored twice [h0,h1,h1,h2,h2,...], +4 pad per 320 ->
// frame f's folded 612-float ext view is CONTIGUOUS at word 324f. Fold &
// region selects vanish (one t>=320 compare in the W stream); frame/epilogue
// addrs are compile-time imms; f=999 wrap staged into the second copy of
// half-1000 (copies legitimately differ there). Bank math: quad starts
// (4g+16r+4k)%32 -> 8 residues x 8 lanes, optimal for ds_read_b128.

#define S_LEN 160000
#define FN    1000
#define NF    16
#define BLOCK 256
#define NBLK  (2 * NF + 2)                    // 34 D-blocks of 160
#define LDSZ  (160 * NBLK + 4 * (NBLK / 2))   // 5508 floats = 22.0 KB

__global__ __launch_bounds__(BLOCK) void xcorr_kernel(const float* __restrict__ x,
                                                      float* __restrict__ out) {
    __shared__ __align__(16) float lds[LDSZ];
    const int tid   = threadIdx.x;
    const int b     = blockIdx.y;
    const int fbase = blockIdx.x * NF;
    const long bOff = (long)b * S_LEN;

    // ---- stage D: block m holds z-half H = fbase + (m+1)>>1; even m = "copy2",
    // odd m = "copy1". Frame f's ext view = blocks 2f..2f+3 (contiguous).
    // Wrap frame 999: copy2(1000) <- x[0:160), copy1(1001) <- x[160:320);
    // copy1(1000) stays zeros (xp pad) via the bounds check.
    for (int j = 4 * tid; j < 160 * NBLK; j += 4 * BLOCK) {
        const int m = j / 160;
        const int i = j - 160 * m;
        const int H = fbase + ((m + 1) >> 1);
        int si = 160 * H + i;
        if (H == 1000 && !(m & 1)) si = i;          // wrap part 1
        if (H == 1001 &&  (m & 1)) si = 160 + i;    // wrap part 2
        const int dst = j + 4 * (m >> 1);           // +4 pad per 2 blocks
        if (si + 3 < S_LEN) {
            *(float4*)&lds[dst] = *(const float4*)&x[bOff + si];
        } else {
#pragma unroll
            for (int e = 0; e < 4; ++e)
                lds[dst + e] = (si + e < S_LEN) ? x[bOff + si + e] : 0.f;
        }
    }
    __syncthreads();

    // ---- compute: group g = frame, 16 lanes, lane r covers taus 33+16r..+15
    const int g    = tid >> 4;
    const int r    = tid & 15;
    const int f    = fbase + g;
    const int tau0 = 33 + 16 * r;
    const int wb   = tau0 - 1;                 // 32+16r, multiple of 4
    const float* E = &lds[324 * g];            // contiguous folded ext view

    float acc[16];
#pragma unroll
    for (int c = 0; c < 16; ++c) acc[c] = 0.f;
    float W[20];        // ext[wb+m] at slot m % 20 (rotation period 5)
    float FQ[2][4];     // frame quad k at slot k & 1 (distance-2 prefetch)

#pragma unroll
    for (int j = 0; j < 5; ++j) {              // m = 0..19; wb+16 <= 288 < 320
        const float4 q = *(const float4*)&E[wb + 4 * j];
        W[4*j] = q.x; W[4*j+1] = q.y; W[4*j+2] = q.z; W[4*j+3] = q.w;
    }
#pragma unroll
    for (int j = 0; j < 2; ++j) {
        const float4 q = *(const float4*)&E[4 * j];
        FQ[j][0] = q.x; FQ[j][1] = q.y; FQ[j][2] = q.z; FQ[j][3] = q.w;
    }

    float Tsum = 0.f, e0 = 0.f;

#pragma unroll 1
    for (int ko = 0; ko < 8; ++ko) {           // 80 rounds = 8 x 10 (lcm of 5,2)
#pragma unroll
        for (int ki = 0; ki < 10; ++ki) {
            const int k  = 10 * ko + ki;
            const int s5 = ki % 5;             // k mod 5 (static)
#pragma unroll
            for (int d = 0; d < 4; ++d) {
                const float fv = FQ[ki & 1][d];
#pragma unroll
                for (int c = 0; c < 16; ++c)
                    acc[c] = fmaf(fv, W[(1 + 4 * s5 + d + c) % 20], acc[c]);
                const float tv = W[(1 + 4 * s5 + d) % 20];   // ext[tau0+4k+d]
                Tsum = fmaf(tv, tv, Tsum);                   // e_tau[tau0] terms
                e0   = fmaf(fv, fv, e0);                     // frame energy
            }
            // prefetch ext quad k+5 (t = wb+4k+20..23; one boundary select)
            {
                const int t = wb + 4 * k + 20;
                const float4 q = *(const float4*)&E[t + ((t >= 320) ? 4 : 0)];
                W[(4*s5 + 0) % 20] = q.x; W[(4*s5 + 1) % 20] = q.y;
                W[(4*s5 + 2) % 20] = q.z; W[(4*s5 + 3) % 20] = q.w;
            }
            // prefetch frame quad k+2 (fo = 4k+8 < 320 when used; imm addr)
            {
                const float4 q = *(const float4*)&E[4 * k + 8];
                FQ[ki & 1][0] = q.x; FQ[ki & 1][1] = q.y;
                FQ[ki & 1][2] = q.z; FQ[ki & 1][3] = q.w;
            }
        }
    }

    // ---- epilogue: e_tau chain (pv/sv are compile-time-offset reads off E)
    if (f < FN && r < 14) {
        float* op = &out[((long)(b * FN + f)) * 224 + 16 * r];
        float et = Tsum;                       // e_tau[tau0]
#pragma unroll
        for (int q = 0; q < 4; ++q) {
            float res[4];
#pragma unroll
            for (int e = 0; e < 4; ++e) {
                const int c = 4 * q + e;
                const float den = e0 + et + 1e-5f;
                res[e] = 2.f * acc[c] * __builtin_amdgcn_rcpf(den);
                if (c < 15) {
                    const float pv = E[tau0 + c];           // ext[u], u<320
                    const float sv = E[tau0 + c + 324];     // ext[u+320] (+4 pad)
                    et += sv * sv - pv * pv;
                }
            }
            *(float4*)&op[4 * q] = make_float4(res[0], res[1], res[2], res[3]);
        }
    }
}

extern "C" void kernel_launch(void* const* d_in, const int* in_sizes, int n_in,
                              void* d_out, int out_size, void* d_ws, size_t ws_size,
                              hipStream_t stream) {
    const float* x = (const float*)d_in[0];
    float* out = (float*)d_out;
    dim3 grid((FN + NF - 1) / NF, 32);   // (63, 32) = 2016 blocks
    dim3 block(BLOCK);
    hipLaunchKernelGGL(xcorr_kernel, grid, block, 0, stream, x, out);
}

// Round 6
// 136.306 us; speedup vs baseline: 1.0460x; 1.0460x over previous
//
#include <hip/hip_runtime.h>

// XCorrExt: B=32, S=160000, N=320, H=160, TAU=257, LAG_CUT=33
// out[b,f,tau-33] = 2*num/(e0 + e_tau + 1e-5), tau in [33,256]
// num[f,tau] = sum_n ext_f[tau+n]*frame_f[n]; frame_f[n] = z[160f+n]
//
// R6: stride-14 tau assignment. LDS services wide ops in 16-lane phases;
// R5's stride-16 lanes gave start banks {0,16} inside a phase (8-way serial,
// 1.16e7 conflict cycles). 14r mod 32 hits 16 DISTINCT even residues ->
// every phase covers all 32 banks at 2-way (free). 16 lanes x 14 taus = 224
// exact (zero dead lanes). D-layout (halves duplicated, stride 320/frame):
// frame g's folded 612-float ext view contiguous at 320g; f=999 wrap staged
// into the duplicate half copies. acc[14]+W[24]+FQ[3][4] ~= 50 VGPRs -> no
// spill at the allocator's 64 target. All LDS offsets are compile-time imms.

#define S_LEN 160000
#define FN    1000
#define NF    16
#define BLOCK 256
#define LDSZ  (160 * 34)   // 5440 floats = 21.75 KB

__global__ __launch_bounds__(BLOCK) void xcorr_kernel(const float* __restrict__ x,
                                                      float* __restrict__ out) {
    __shared__ __align__(16) float lds[LDSZ];
    const int tid   = threadIdx.x;
    const int b     = blockIdx.y;
    const int fbase = blockIdx.x * NF;
    const long bOff = (long)b * S_LEN;

    // ---- stage D: L-block m (160 floats) holds z-half fbase+((m+1)>>1);
    // odd m = copy1, even m = copy2. Frame g's ext view = L[320g .. 320g+612).
    // f=999 wrap: copy2 of half-1000 <- x[0:160), copy1 of half-1001 <- x[160:320).
    for (int j = 4 * tid; j < LDSZ; j += 4 * BLOCK) {
        const int m = j / 160;
        const int i = j - 160 * m;
        const int H = fbase + ((m + 1) >> 1);
        int si = 160 * H + i;
        if (H == 1000 && !(m & 1)) si = i;          // wrap part 1
        if (H == 1001 &&  (m & 1)) si = 160 + i;    // wrap part 2
        if (si + 3 < S_LEN) {
            *(float4*)&lds[j] = *(const float4*)&x[bOff + si];
        } else {
#pragma unroll
            for (int e = 0; e < 4; ++e)
                lds[j + e] = (si + e < S_LEN) ? x[bOff + si + e] : 0.f;
        }
    }
    __syncthreads();

    // ---- compute: group g = frame, lane r covers taus 33+14r .. +13
    const int g    = tid >> 4;
    const int r    = tid & 15;
    const int f    = fbase + g;
    const int tau0 = 33 + 14 * r;
    const int wb   = tau0 - 1;            // 32+14r (even, 8B-aligned)
    const float* E = &lds[320 * g];       // contiguous folded ext view (612)

    float acc[14];
#pragma unroll
    for (int c = 0; c < 14; ++c) acc[c] = 0.f;
    float W[24];      // ext[wb+o] at slot o % 24 (ring, refill dist ~2.5 rounds)
    float FQ[3][4];   // frame quad k at slot k % 3

#pragma unroll
    for (int j = 0; j < 6; ++j) {         // offsets 0..23 (wb+23 <= 265 < 612)
        const float2 qa = *(const float2*)&E[wb + 4 * j];
        const float2 qb = *(const float2*)&E[wb + 4 * j + 2];
        W[4*j] = qa.x; W[4*j+1] = qa.y; W[4*j+2] = qb.x; W[4*j+3] = qb.y;
    }
#pragma unroll
    for (int j = 0; j < 3; ++j) {         // frame quads 0..2
        const float4 q = *(const float4*)&E[4 * j];
        FQ[j][0] = q.x; FQ[j][1] = q.y; FQ[j][2] = q.z; FQ[j][3] = q.w;
    }

    float Tsum = 0.f, e0 = 0.f;

#define XROUND(k_, kk_)                                                        \
    do {                                                                       \
        _Pragma("unroll")                                                      \
        for (int d = 0; d < 4; ++d) {                                          \
            const float fv = FQ[(kk_) % 3][d];                                 \
            _Pragma("unroll")                                                  \
            for (int c = 0; c < 14; ++c)                                       \
                acc[c] = fmaf(fv, W[(4 * (kk_) + 1 + d + c) % 24], acc[c]);    \
            const float tv = W[(4 * (kk_) + 1 + d) % 24];                      \
            Tsum = fmaf(tv, tv, Tsum);                                         \
            e0   = fmaf(fv, fv, e0);                                           \
        }                                                                      \
        { /* refill ext quad: offsets 4k+24..27 -> slots (4kk..4kk+3)%24 */    \
            const float2 qa = *(const float2*)&E[wb + 4 * (k_) + 24];          \
            const float2 qb = *(const float2*)&E[wb + 4 * (k_) + 26];          \
            W[(4 * (kk_) + 0) % 24] = qa.x; W[(4 * (kk_) + 1) % 24] = qa.y;    \
            W[(4 * (kk_) + 2) % 24] = qb.x; W[(4 * (kk_) + 3) % 24] = qb.y;    \
        }                                                                      \
        { /* refill frame quad k+3 -> slot kk%3 (after use this round) */      \
            const float4 q = *(const float4*)&E[4 * (k_) + 12];                \
            FQ[(kk_) % 3][0] = q.x; FQ[(kk_) % 3][1] = q.y;                    \
            FQ[(kk_) % 3][2] = q.z; FQ[(kk_) % 3][3] = q.w;                    \
        }                                                                      \
    } while (0)

#pragma unroll 1
    for (int ko = 0; ko < 13; ++ko) {     // 78 rounds (unroll 6 = lcm(6,3))
#pragma unroll
        for (int kk = 0; kk < 6; ++kk) {
            const int k = 6 * ko + kk;
            XROUND(k, kk);
        }
    }
#pragma unroll
    for (int kt = 0; kt < 2; ++kt) {      // rounds 78,79 (78 % 6 == 0, % 3 == 0)
        const int k = 78 + kt;
        XROUND(k, kt);
    }
#undef XROUND

    // ---- epilogue: e_tau chain + normalize (scalar reads, 14r bank-spread)
    if (f < FN) {
        float* op = &out[((long)(b * FN + f)) * 224 + 14 * r];
        float et = Tsum;                  // e_tau[tau0]
        float res[14];
#pragma unroll
        for (int c = 0; c < 14; ++c) {
            const float den = e0 + et + 1e-5f;
            res[c] = 2.f * acc[c] * __builtin_amdgcn_rcpf(den);
            if (c < 13) {
                const float pv = E[tau0 + c];         // ext[u], u < 320
                const float sv = E[tau0 + c + 320];   // ext[u+320] (folded view)
                et += sv * sv - pv * pv;
            }
        }
#pragma unroll
        for (int q = 0; q < 7; ++q)       // 14r even -> 8B-aligned float2 stores
            *(float2*)&op[2 * q] = make_float2(res[2*q], res[2*q+1]);
    }
}

extern "C" void kernel_launch(void* const* d_in, const int* in_sizes, int n_in,
                              void* d_out, int out_size, void* d_ws, size_t ws_size,
                              hipStream_t stream) {
    const float* x = (const float*)d_in[0];
    float* out = (float*)d_out;
    dim3 grid((FN + NF - 1) / NF, 32);    // (63, 32) = 2016 blocks
    dim3 block(BLOCK);
    hipLaunchKernelGGL(xcorr_kernel, grid, block, 0, stream, x, out);
}